// Round 4
// baseline (389.449 us; speedup 1.0000x reference)
//
#include <hip/hip_runtime.h>
#include <hip/hip_bf16.h>

// BERT_SCL: loss = 0.9 * supcon(cls_emb, labels) + 0.1 * CE(pooled@W.T + b, labels)
// d_out[0] = loss, d_out[1..57344] = logits (8192 x 7, f32)
//
// supcon: en = rows of cls_emb normalized, scaled by 1/sqrt(TEMP), cast bf16.
// S_ij = en_i . en_j = cos/TEMP <= M = 1/TEMP  ->  fixed-max logsumexp.
// S symmetric + symmetric positive mask -> only tiles bi <= bj (2080 of 4096),
// off-diagonal tiles emit row-sums AND column-sums. Supertile swizzle (8x8)
// keeps the co-resident panel working set ~3 MB (fits per-XCD L2).
// R3 lesson: kernel is latency-bound; VGPR 116 dropped co-residency 5->4
// blocks/CU. This round: launch_bounds(256,5) + streamed bF to fit 102 regs.

#define B_N 8192
#define D_K 768
#define NLAB 7
#define MBOUND 3.3333333333333335f /* 1/TEMP */
#define RTINV 1.8257418583505538f  /* 1/sqrt(TEMP) */

typedef short s16x8 __attribute__((ext_vector_type(8)));
typedef float f32x4 __attribute__((ext_vector_type(4)));

__device__ __forceinline__ void gl2lds16(const void* g, void* l) {
  __builtin_amdgcn_global_load_lds(
      (const __attribute__((address_space(1))) void*)g,
      (__attribute__((address_space(3))) void*)l, 16, 0, 0);
}

// ---- kernel 1: normalize cls rows -> bf16 en (scaled by 1/sqrt(TEMP)) ----
__global__ __launch_bounds__(256) void k_norm(const float* __restrict__ cls,
                                              unsigned short* __restrict__ en) {
  int row = blockIdx.x * 4 + (threadIdx.x >> 6);
  int lane = threadIdx.x & 63;
  const float4* src = (const float4*)(cls + (size_t)row * D_K);
  float4 x[3];
  float ss = 0.f;
#pragma unroll
  for (int j = 0; j < 3; ++j) {
    x[j] = src[j * 64 + lane];
    ss += x[j].x * x[j].x + x[j].y * x[j].y + x[j].z * x[j].z + x[j].w * x[j].w;
  }
#pragma unroll
  for (int m = 1; m < 64; m <<= 1) ss += __shfl_xor(ss, m);
  float sc = rsqrtf(ss) * RTINV;
  ushort4* dst = (ushort4*)(en + (size_t)row * D_K);
#pragma unroll
  for (int j = 0; j < 3; ++j) {
    const float* xv = reinterpret_cast<const float*>(&x[j]);
    ushort4 o;
    unsigned short* ov = reinterpret_cast<unsigned short*>(&o);
#pragma unroll
    for (int k = 0; k < 4; ++k) {
      __hip_bfloat16 h = __float2bfloat16(xv[k] * sc);
      ov[k] = *reinterpret_cast<unsigned short*>(&h);
    }
    dst[j * 64 + lane] = o;
  }
}

// ---- kernel 1b: label histogram, register counters -> wave reduce -> few atomics ----
__global__ __launch_bounds__(256) void k_hist(const int* __restrict__ labels,
                                              int* __restrict__ hist) {
  int cnt[NLAB];
#pragma unroll
  for (int c = 0; c < NLAB; ++c) cnt[c] = 0;
  int base = blockIdx.x * 1024 + threadIdx.x;  // 8 blocks x 256 thr x 4 labels
#pragma unroll
  for (int j = 0; j < 4; ++j) {
    int lab = labels[base + j * 256];
#pragma unroll
    for (int c = 0; c < NLAB; ++c) cnt[c] += (lab == c);
  }
#pragma unroll
  for (int c = 0; c < NLAB; ++c)
#pragma unroll
    for (int m = 1; m < 64; m <<= 1) cnt[c] += __shfl_xor(cnt[c], m);
  if ((threadIdx.x & 63) == 0)
#pragma unroll
    for (int c = 0; c < NLAB; ++c) atomicAdd(&hist[c], cnt[c]);
}

// ---- kernel 2: logits = pooled @ W.T + b ; per-row CE to array ----
__global__ __launch_bounds__(256) void k_logits_ce(
    const float* __restrict__ pooled, const int* __restrict__ labels,
    const float* __restrict__ W, const float* __restrict__ bias,
    float* __restrict__ logits_out, float* __restrict__ celoss) {
  int row = blockIdx.x * 4 + (threadIdx.x >> 6);
  int lane = threadIdx.x & 63;
  const float4* p4 = (const float4*)(pooled + (size_t)row * D_K);
  float acc[NLAB];
#pragma unroll
  for (int c = 0; c < NLAB; ++c) acc[c] = 0.f;
#pragma unroll
  for (int j = 0; j < 3; ++j) {
    float4 x = p4[j * 64 + lane];
#pragma unroll
    for (int c = 0; c < NLAB; ++c) {
      float4 w = ((const float4*)(W + c * D_K))[j * 64 + lane];
      acc[c] += x.x * w.x + x.y * w.y + x.z * w.z + x.w * w.w;
    }
  }
#pragma unroll
  for (int c = 0; c < NLAB; ++c)
#pragma unroll
    for (int m = 1; m < 64; m <<= 1) acc[c] += __shfl_xor(acc[c], m);
  if (lane == 0) {
    float l[NLAB], mx = -1e30f;
#pragma unroll
    for (int c = 0; c < NLAB; ++c) { l[c] = acc[c] + bias[c]; mx = fmaxf(mx, l[c]); }
    float se = 0.f;
#pragma unroll
    for (int c = 0; c < NLAB; ++c) se += __expf(l[c] - mx);
    float lse = mx + __logf(se);
    celoss[row] = lse - l[labels[row]];
    float* o = logits_out + (size_t)row * NLAB;
#pragma unroll
    for (int c = 0; c < NLAB; ++c) o[c] = l[c];
  }
}

// ---- kernel 3: S-tiles via bf16 MFMA, upper-triangular, supertile order ----
__global__ __launch_bounds__(256, 5) void k_scl(const unsigned short* __restrict__ en,
                                                const int* __restrict__ labels,
                                                float* __restrict__ rse,
                                                float* __restrict__ rsp) {
  __shared__ __align__(16) unsigned short As[128 * 64];
  __shared__ __align__(16) unsigned short Bs[128 * 64];

  // supertile decode: 8x8-block supertiles over the triangle, row-major;
  // diag ST = 36 blocks (local triangle), off-diag ST = 64.
  int rem = blockIdx.x;
  int BI = 0, BJ = 0;
  for (;;) {
    int sz = (BI == BJ) ? 36 : 64;
    if (rem < sz) break;
    rem -= sz;
    if (++BJ == 8) { ++BI; BJ = BI; }
  }
  int bi, bj;
  if (BI == BJ) {
    int r = 0, w = 8;
    while (rem >= w) { rem -= w; ++r; --w; }
    bi = BI * 8 + r;
    bj = BJ * 8 + r + rem;
  } else {
    bi = BI * 8 + (rem >> 3);
    bj = BJ * 8 + (rem & 7);
  }

  const int i0 = bi * 128, j0 = bj * 128;
  const int tid = threadIdx.x, wv = tid >> 6, lane = tid & 63;
  const int quad = lane >> 4, cix = lane & 15;
  const int rowTile = 64 * (wv >> 1), colTile = 64 * (wv & 1);

  f32x4 acc[4][4] = {};

  for (int kc = 0; kc < 12; ++kc) {
    __syncthreads();
#pragma unroll
    for (int it = 0; it < 4; ++it) {
      int s = it * 256 + tid;
      int r = s >> 3;
      int c = ((s & 7) - r) & 7;  // inverse of write swizzle
      int lbase = (it * 256 + wv * 64) * 16;  // wave-uniform LDS base (bytes)
      gl2lds16(en + (size_t)(i0 + r) * D_K + kc * 64 + c * 8, (char*)As + lbase);
      gl2lds16(en + (size_t)(j0 + r) * D_K + kc * 64 + c * 8, (char*)Bs + lbase);
    }
    __syncthreads();
#pragma unroll
    for (int h = 0; h < 2; ++h) {
      const int cc = quad + 4 * h;
      s16x8 aF[4];
#pragma unroll
      for (int mt = 0; mt < 4; ++mt) {
        int r = rowTile + 16 * mt + cix;
        aF[mt] = *reinterpret_cast<const s16x8*>((const char*)As +
                                                 (r * 8 + ((cc + r) & 7)) * 16);
      }
#pragma unroll
      for (int nt = 0; nt < 4; ++nt) {  // bF streamed: 1 live frag, not 4
        int r = colTile + 16 * nt + cix;
        s16x8 bF = *reinterpret_cast<const s16x8*>((const char*)Bs +
                                                   (r * 8 + ((cc + r) & 7)) * 16);
#pragma unroll
        for (int mt = 0; mt < 4; ++mt)
          acc[mt][nt] = __builtin_amdgcn_mfma_f32_16x16x32_bf16(
              aF[mt], bF, acc[mt][nt], 0, 0, 0);
      }
    }
  }

  // ---- epilogue (diag / non-diag split) ----
  int lcol[4];
#pragma unroll
  for (int nt = 0; nt < 4; ++nt) lcol[nt] = labels[j0 + colTile + 16 * nt + cix];

  if (bi != bj) {
    float ce_col[4] = {0.f, 0.f, 0.f, 0.f};
    float cp_col[4] = {0.f, 0.f, 0.f, 0.f};
#pragma unroll
    for (int mt = 0; mt < 4; ++mt) {
      int rowbase = i0 + rowTile + 16 * mt + quad * 4;
      int4 lr = *reinterpret_cast<const int4*>(labels + rowbase);
      const int* lrp = reinterpret_cast<const int*>(&lr);
      float rs_e[4] = {0.f, 0.f, 0.f, 0.f}, rs_p[4] = {0.f, 0.f, 0.f, 0.f};
#pragma unroll
      for (int nt = 0; nt < 4; ++nt) {
        int lc = lcol[nt];
#pragma unroll
        for (int rg = 0; rg < 4; ++rg) {
          float s = acc[mt][nt][rg];
          float e = __expf(s - MBOUND);
          float p = (lrp[rg] == lc) ? s : 0.f;
          rs_e[rg] += e;
          rs_p[rg] += p;
          ce_col[nt] += e;
          cp_col[nt] += p;
        }
      }
#pragma unroll
      for (int rg = 0; rg < 4; ++rg) {
#pragma unroll
        for (int m = 1; m <= 8; m <<= 1) {
          rs_e[rg] += __shfl_xor(rs_e[rg], m);
          rs_p[rg] += __shfl_xor(rs_p[rg], m);
        }
      }
      if (cix == 0) {
#pragma unroll
        for (int rg = 0; rg < 4; ++rg) {
          atomicAdd(&rse[rowbase + rg], rs_e[rg]);
          atomicAdd(&rsp[rowbase + rg], rs_p[rg]);
        }
      }
    }
    // column side: S_ji = S_ij
#pragma unroll
    for (int nt = 0; nt < 4; ++nt) {
      ce_col[nt] += __shfl_xor(ce_col[nt], 16);
      ce_col[nt] += __shfl_xor(ce_col[nt], 32);
      cp_col[nt] += __shfl_xor(cp_col[nt], 16);
      cp_col[nt] += __shfl_xor(cp_col[nt], 32);
    }
    if (quad == 0) {
#pragma unroll
      for (int nt = 0; nt < 4; ++nt) {
        int gcol = j0 + colTile + 16 * nt + cix;
        atomicAdd(&rse[gcol], ce_col[nt]);
        atomicAdd(&rsp[gcol], cp_col[nt]);
      }
    }
  } else {
    // diagonal block: row side only, with diagonal exclusion
#pragma unroll
    for (int mt = 0; mt < 4; ++mt) {
      int rowbase = i0 + rowTile + 16 * mt + quad * 4;
      int4 lr = *reinterpret_cast<const int4*>(labels + rowbase);
      const int* lrp = reinterpret_cast<const int*>(&lr);
      float rs_e[4] = {0.f, 0.f, 0.f, 0.f}, rs_p[4] = {0.f, 0.f, 0.f, 0.f};
#pragma unroll
      for (int nt = 0; nt < 4; ++nt) {
        int gcol = j0 + colTile + 16 * nt + cix;
        int lc = lcol[nt];
#pragma unroll
        for (int rg = 0; rg < 4; ++rg) {
          float s = acc[mt][nt][rg];
          bool dg = (rowbase + rg) == gcol;
          rs_e[rg] += dg ? 0.f : __expf(s - MBOUND);
          rs_p[rg] += ((lrp[rg] == lc) && !dg) ? s : 0.f;
        }
      }
#pragma unroll
      for (int rg = 0; rg < 4; ++rg) {
#pragma unroll
        for (int m = 1; m <= 8; m <<= 1) {
          rs_e[rg] += __shfl_xor(rs_e[rg], m);
          rs_p[rg] += __shfl_xor(rs_p[rg], m);
        }
      }
      if (cix == 0) {
#pragma unroll
        for (int rg = 0; rg < 4; ++rg) {
          atomicAdd(&rse[rowbase + rg], rs_e[rg]);
          atomicAdd(&rsp[rowbase + rg], rs_p[rg]);
        }
      }
    }
  }
}

// ---- kernel 4: per-row 0.9*per_anchor + (0.1/B)*ce -> contr ----
__global__ __launch_bounds__(256) void k_rowfinal(const float* __restrict__ rse,
                                                  const float* __restrict__ rsp,
                                                  const int* __restrict__ labels,
                                                  const int* __restrict__ hist,
                                                  const float* __restrict__ celoss,
                                                  float* __restrict__ contr) {
  int i = blockIdx.x * 256 + threadIdx.x;
  int ni = hist[labels[i]] - 1;
  float per = 0.f;
  if (ni > 0) per = MBOUND + __logf(rse[i]) - rsp[i] / (float)ni;
  float v = 0.9f * per + (0.1f / (float)B_N) * celoss[i];
#pragma unroll
  for (int m = 1; m < 64; m <<= 1) v += __shfl_xor(v, m);
  if ((threadIdx.x & 63) == 0) atomicAdd(contr, v);
}

// ---- kernel 5: final scalar copy ----
__global__ void k_final(const float* __restrict__ contr, float* __restrict__ out) {
  if (threadIdx.x == 0 && blockIdx.x == 0) out[0] = contr[0];
}

extern "C" void kernel_launch(void* const* d_in, const int* in_sizes, int n_in,
                              void* d_out, int out_size, void* d_ws, size_t ws_size,
                              hipStream_t stream) {
  const float* cls    = (const float*)d_in[0];
  const float* pooled = (const float*)d_in[1];
  const int*   labels = (const int*)d_in[2];
  const float* W      = (const float*)d_in[3];
  const float* bias   = (const float*)d_in[4];
  float* out = (float*)d_out;

  // workspace layout (~12.7 MB)
  char* ws = (char*)d_ws;
  unsigned short* en = (unsigned short*)ws;            // 8192*768*2 = 12582912 B
  size_t off = (size_t)B_N * D_K * 2;
  float* rse    = (float*)(ws + off);                  // 8192 f32
  float* rsp    = (float*)(ws + off + 32768);          // 8192 f32
  int*   hist   = (int*)(ws + off + 65536);            // 7 int (pad 32)
  float* contr  = (float*)(ws + off + 65568);          // 1 f32
  float* celoss = (float*)(ws + off + 65536 + 4096);   // 8192 f32 (written fully)

  hipMemsetAsync(ws + off, 0, 65572, stream);  // zero rse/rsp/hist/contr

  k_norm<<<B_N / 4, 256, 0, stream>>>(cls, en);
  k_hist<<<8, 256, 0, stream>>>(labels, hist);
  k_logits_ce<<<B_N / 4, 256, 0, stream>>>(pooled, labels, W, bias, out + 1, celoss);
  k_scl<<<2080, 256, 0, stream>>>(en, labels, rse, rsp);
  k_rowfinal<<<B_N / 256, 256, 0, stream>>>(rse, rsp, labels, hist, celoss, contr);
  k_final<<<1, 64, 0, stream>>>(contr, out);
}

// Round 5
// 307.547 us; speedup vs baseline: 1.2663x; 1.2663x over previous
//
#include <hip/hip_runtime.h>
#include <hip/hip_bf16.h>

// BERT_SCL: loss = 0.9 * supcon(cls_emb, labels) + 0.1 * CE(pooled@W.T + b, labels)
// d_out[0] = loss, d_out[1..57344] = logits (8192 x 7, f32)
//
// supcon: en = rows of cls_emb normalized, scaled by 1/sqrt(TEMP), cast bf16.
// S_ij = en_i . en_j <= M = 1/TEMP -> fixed-max logsumexp (no online rescale).
// KEY ALGEBRA (r4): possum_i = sum_{j in class} S_ij - S_ii
//                            = en_i . T_{l_i} - ||en_i||^2,  T_c = sum_{l_j=c} en_j.
// The positive mask is linear in S -> only lse needs the big GEMM. k_scl now
// computes ONLY exp-sums (rse). possum comes from a 7x768 class-sum (k_classum)
// + per-row dot in k_rowfinal.
// S symmetric -> only tiles bi <= bj (2080), off-diag tiles emit row AND col
// exp-sums. Supertile swizzle (8x8) keeps panel working set L2-friendly.
// r4 lesson: launch_bounds(256,5) spilled acc to scratch (VGPR 48, 363 MB
// writes) -> never force the tier; shrink live state instead (done here).

#define B_N 8192
#define D_K 768
#define NLAB 7
#define MBOUND 3.3333333333333335f /* 1/TEMP */
#define RTINV 1.8257418583505538f  /* 1/sqrt(TEMP) */

typedef short s16x8 __attribute__((ext_vector_type(8)));
typedef float f32x4 __attribute__((ext_vector_type(4)));

__device__ __forceinline__ void gl2lds16(const void* g, void* l) {
  __builtin_amdgcn_global_load_lds(
      (const __attribute__((address_space(1))) void*)g,
      (__attribute__((address_space(3))) void*)l, 16, 0, 0);
}

__device__ __forceinline__ float bf16u_to_f(unsigned short u) {
  unsigned int w = ((unsigned int)u) << 16;
  return __uint_as_float(w);
}

// ---- kernel 1: normalize cls rows -> bf16 en (scaled by 1/sqrt(TEMP)) ----
__global__ __launch_bounds__(256) void k_norm(const float* __restrict__ cls,
                                              unsigned short* __restrict__ en) {
  int row = blockIdx.x * 4 + (threadIdx.x >> 6);
  int lane = threadIdx.x & 63;
  const float4* src = (const float4*)(cls + (size_t)row * D_K);
  float4 x[3];
  float ss = 0.f;
#pragma unroll
  for (int j = 0; j < 3; ++j) {
    x[j] = src[j * 64 + lane];
    ss += x[j].x * x[j].x + x[j].y * x[j].y + x[j].z * x[j].z + x[j].w * x[j].w;
  }
#pragma unroll
  for (int m = 1; m < 64; m <<= 1) ss += __shfl_xor(ss, m);
  float sc = rsqrtf(ss) * RTINV;
  ushort4* dst = (ushort4*)(en + (size_t)row * D_K);
#pragma unroll
  for (int j = 0; j < 3; ++j) {
    const float* xv = reinterpret_cast<const float*>(&x[j]);
    ushort4 o;
    unsigned short* ov = reinterpret_cast<unsigned short*>(&o);
#pragma unroll
    for (int k = 0; k < 4; ++k) {
      __hip_bfloat16 h = __float2bfloat16(xv[k] * sc);
      ov[k] = *reinterpret_cast<unsigned short*>(&h);
    }
    dst[j * 64 + lane] = o;
  }
}

// ---- kernel 1b: label histogram ----
__global__ __launch_bounds__(256) void k_hist(const int* __restrict__ labels,
                                              int* __restrict__ hist) {
  int cnt[NLAB];
#pragma unroll
  for (int c = 0; c < NLAB; ++c) cnt[c] = 0;
  int base = blockIdx.x * 1024 + threadIdx.x;
#pragma unroll
  for (int j = 0; j < 4; ++j) {
    int lab = labels[base + j * 256];
#pragma unroll
    for (int c = 0; c < NLAB; ++c) cnt[c] += (lab == c);
  }
#pragma unroll
  for (int c = 0; c < NLAB; ++c)
#pragma unroll
    for (int m = 1; m < 64; m <<= 1) cnt[c] += __shfl_xor(cnt[c], m);
  if ((threadIdx.x & 63) == 0)
#pragma unroll
    for (int c = 0; c < NLAB; ++c) atomicAdd(&hist[c], cnt[c]);
}

// ---- kernel 1c: class sums T[c][k] = sum_{rows with label c} en[row][k] ----
// 48 blocks: group g = blockIdx/3 covers rows [g*512,(g+1)*512); k = (blockIdx%3)*256+tid.
__global__ __launch_bounds__(256) void k_classum(const unsigned short* __restrict__ en,
                                                 const int* __restrict__ labels,
                                                 float* __restrict__ T) {
  int g = blockIdx.x / 3;
  int kk = (blockIdx.x % 3) * 256 + threadIdx.x;
  float acc[NLAB];
#pragma unroll
  for (int c = 0; c < NLAB; ++c) acc[c] = 0.f;
  int r0 = g * 512;
  for (int r = 0; r < 512; ++r) {
    int row = r0 + r;
    int lab = labels[row];
    float x = bf16u_to_f(en[(size_t)row * D_K + kk]);
#pragma unroll
    for (int c = 0; c < NLAB; ++c) acc[c] += (lab == c) ? x : 0.f;
  }
#pragma unroll
  for (int c = 0; c < NLAB; ++c) atomicAdd(&T[c * D_K + kk], acc[c]);
}

// ---- kernel 2: logits = pooled @ W.T + b ; per-row CE to array ----
__global__ __launch_bounds__(256) void k_logits_ce(
    const float* __restrict__ pooled, const int* __restrict__ labels,
    const float* __restrict__ W, const float* __restrict__ bias,
    float* __restrict__ logits_out, float* __restrict__ celoss) {
  int row = blockIdx.x * 4 + (threadIdx.x >> 6);
  int lane = threadIdx.x & 63;
  const float4* p4 = (const float4*)(pooled + (size_t)row * D_K);
  float acc[NLAB];
#pragma unroll
  for (int c = 0; c < NLAB; ++c) acc[c] = 0.f;
#pragma unroll
  for (int j = 0; j < 3; ++j) {
    float4 x = p4[j * 64 + lane];
#pragma unroll
    for (int c = 0; c < NLAB; ++c) {
      float4 w = ((const float4*)(W + c * D_K))[j * 64 + lane];
      acc[c] += x.x * w.x + x.y * w.y + x.z * w.z + x.w * w.w;
    }
  }
#pragma unroll
  for (int c = 0; c < NLAB; ++c)
#pragma unroll
    for (int m = 1; m < 64; m <<= 1) acc[c] += __shfl_xor(acc[c], m);
  if (lane == 0) {
    float l[NLAB], mx = -1e30f;
#pragma unroll
    for (int c = 0; c < NLAB; ++c) { l[c] = acc[c] + bias[c]; mx = fmaxf(mx, l[c]); }
    float se = 0.f;
#pragma unroll
    for (int c = 0; c < NLAB; ++c) se += __expf(l[c] - mx);
    float lse = mx + __logf(se);
    celoss[row] = lse - l[labels[row]];
    float* o = logits_out + (size_t)row * NLAB;
#pragma unroll
    for (int c = 0; c < NLAB; ++c) o[c] = l[c];
  }
}

// ---- kernel 3: exp-sum S-tiles via bf16 MFMA, upper-triangular, supertile order ----
__global__ __launch_bounds__(256) void k_scl(const unsigned short* __restrict__ en,
                                             float* __restrict__ rse) {
  __shared__ __align__(16) unsigned short As[128 * 64];
  __shared__ __align__(16) unsigned short Bs[128 * 64];

  // supertile decode: 8x8-block supertiles over the triangle, row-major;
  // diag ST = 36 blocks (local triangle), off-diag ST = 64.
  int rem = blockIdx.x;
  int BI = 0, BJ = 0;
  for (;;) {
    int sz = (BI == BJ) ? 36 : 64;
    if (rem < sz) break;
    rem -= sz;
    if (++BJ == 8) { ++BI; BJ = BI; }
  }
  int bi, bj;
  if (BI == BJ) {
    int r = 0, w = 8;
    while (rem >= w) { rem -= w; ++r; --w; }
    bi = BI * 8 + r;
    bj = BJ * 8 + r + rem;
  } else {
    bi = BI * 8 + (rem >> 3);
    bj = BJ * 8 + (rem & 7);
  }

  const int i0 = bi * 128, j0 = bj * 128;
  const int tid = threadIdx.x, wv = tid >> 6, lane = tid & 63;
  const int quad = lane >> 4, cix = lane & 15;
  const int rowTile = 64 * (wv >> 1), colTile = 64 * (wv & 1);

  f32x4 acc[4][4] = {};

  for (int kc = 0; kc < 12; ++kc) {
    __syncthreads();
#pragma unroll
    for (int it = 0; it < 4; ++it) {
      int s = it * 256 + tid;
      int r = s >> 3;
      int c = ((s & 7) - r) & 7;  // inverse of write swizzle
      int lbase = (it * 256 + wv * 64) * 16;  // wave-uniform LDS base (bytes)
      gl2lds16(en + (size_t)(i0 + r) * D_K + kc * 64 + c * 8, (char*)As + lbase);
      gl2lds16(en + (size_t)(j0 + r) * D_K + kc * 64 + c * 8, (char*)Bs + lbase);
    }
    __syncthreads();
#pragma unroll
    for (int h = 0; h < 2; ++h) {
      const int cc = quad + 4 * h;
      s16x8 aF[4];
#pragma unroll
      for (int mt = 0; mt < 4; ++mt) {
        int r = rowTile + 16 * mt + cix;
        aF[mt] = *reinterpret_cast<const s16x8*>((const char*)As +
                                                 (r * 8 + ((cc + r) & 7)) * 16);
      }
#pragma unroll
      for (int nt = 0; nt < 4; ++nt) {  // bF streamed: 1 live frag
        int r = colTile + 16 * nt + cix;
        s16x8 bF = *reinterpret_cast<const s16x8*>((const char*)Bs +
                                                   (r * 8 + ((cc + r) & 7)) * 16);
#pragma unroll
        for (int mt = 0; mt < 4; ++mt)
          acc[mt][nt] = __builtin_amdgcn_mfma_f32_16x16x32_bf16(
              aF[mt], bF, acc[mt][nt], 0, 0, 0);
      }
    }
  }

  // ---- epilogue: exp-sums only ----
  if (bi != bj) {
    float ce_col[4] = {0.f, 0.f, 0.f, 0.f};
#pragma unroll
    for (int mt = 0; mt < 4; ++mt) {
      int rowbase = i0 + rowTile + 16 * mt + quad * 4;
      float rs_e[4] = {0.f, 0.f, 0.f, 0.f};
#pragma unroll
      for (int nt = 0; nt < 4; ++nt) {
#pragma unroll
        for (int rg = 0; rg < 4; ++rg) {
          float e = __expf(acc[mt][nt][rg] - MBOUND);
          rs_e[rg] += e;
          ce_col[nt] += e;
        }
      }
#pragma unroll
      for (int rg = 0; rg < 4; ++rg)
#pragma unroll
        for (int m = 1; m <= 8; m <<= 1) rs_e[rg] += __shfl_xor(rs_e[rg], m);
      if (cix == 0)
#pragma unroll
        for (int rg = 0; rg < 4; ++rg) atomicAdd(&rse[rowbase + rg], rs_e[rg]);
    }
    // column side: S_ji = S_ij
#pragma unroll
    for (int nt = 0; nt < 4; ++nt) {
      ce_col[nt] += __shfl_xor(ce_col[nt], 16);
      ce_col[nt] += __shfl_xor(ce_col[nt], 32);
    }
    if (quad == 0)
#pragma unroll
      for (int nt = 0; nt < 4; ++nt)
        atomicAdd(&rse[j0 + colTile + 16 * nt + cix], ce_col[nt]);
  } else {
    // diagonal block: row side only, exclude diagonal element
#pragma unroll
    for (int mt = 0; mt < 4; ++mt) {
      int rowbase = i0 + rowTile + 16 * mt + quad * 4;
      float rs_e[4] = {0.f, 0.f, 0.f, 0.f};
#pragma unroll
      for (int nt = 0; nt < 4; ++nt) {
        int gcol = j0 + colTile + 16 * nt + cix;
#pragma unroll
        for (int rg = 0; rg < 4; ++rg) {
          bool dg = (rowbase + rg) == gcol;
          rs_e[rg] += dg ? 0.f : __expf(acc[mt][nt][rg] - MBOUND);
        }
      }
#pragma unroll
      for (int rg = 0; rg < 4; ++rg)
#pragma unroll
        for (int m = 1; m <= 8; m <<= 1) rs_e[rg] += __shfl_xor(rs_e[rg], m);
      if (cix == 0)
#pragma unroll
        for (int rg = 0; rg < 4; ++rg) atomicAdd(&rse[rowbase + rg], rs_e[rg]);
    }
  }
}

// ---- kernel 4: per-row: possum via en.T[l] - selfdot; combine; 64-slot partials ----
__global__ __launch_bounds__(256) void k_rowfinal(const float* __restrict__ rse,
                                                  const unsigned short* __restrict__ en,
                                                  const float* __restrict__ T,
                                                  const int* __restrict__ labels,
                                                  const int* __restrict__ hist,
                                                  const float* __restrict__ celoss,
                                                  float* __restrict__ contrP) {
  __shared__ float part[4];
  int wv = threadIdx.x >> 6, lane = threadIdx.x & 63;
  int row = blockIdx.x * 4 + wv;
  int l = labels[row];
  const ushort4* e4 = (const ushort4*)(en + (size_t)row * D_K);
  const float4* t4 = (const float4*)(T + (size_t)l * D_K);
  float pd = 0.f, sd = 0.f;
#pragma unroll
  for (int j = 0; j < 3; ++j) {
    ushort4 u = e4[j * 64 + lane];
    float4 t = t4[j * 64 + lane];
    float a0 = bf16u_to_f(u.x), a1 = bf16u_to_f(u.y);
    float a2 = bf16u_to_f(u.z), a3 = bf16u_to_f(u.w);
    pd += a0 * t.x + a1 * t.y + a2 * t.z + a3 * t.w;
    sd += a0 * a0 + a1 * a1 + a2 * a2 + a3 * a3;
  }
#pragma unroll
  for (int m = 1; m < 64; m <<= 1) {
    pd += __shfl_xor(pd, m);
    sd += __shfl_xor(sd, m);
  }
  if (lane == 0) {
    int ni = hist[l] - 1;
    float per = 0.f;
    if (ni > 0) {
      float possum = pd - sd;
      per = MBOUND + __logf(rse[row]) - possum / (float)ni;
    }
    part[wv] = 0.9f * per + (0.1f / (float)B_N) * celoss[row];
  }
  __syncthreads();
  if (threadIdx.x == 0) {
    float v = part[0] + part[1] + part[2] + part[3];
    atomicAdd(&contrP[(blockIdx.x & 63) * 16], v);
  }
}

// ---- kernel 5: reduce 64 partials -> loss ----
__global__ void k_final(const float* __restrict__ contrP, float* __restrict__ out) {
  float v = contrP[threadIdx.x * 16];
#pragma unroll
  for (int m = 1; m < 64; m <<= 1) v += __shfl_xor(v, m);
  if (threadIdx.x == 0) out[0] = v;
}

extern "C" void kernel_launch(void* const* d_in, const int* in_sizes, int n_in,
                              void* d_out, int out_size, void* d_ws, size_t ws_size,
                              hipStream_t stream) {
  const float* cls    = (const float*)d_in[0];
  const float* pooled = (const float*)d_in[1];
  const int*   labels = (const int*)d_in[2];
  const float* W      = (const float*)d_in[3];
  const float* bias   = (const float*)d_in[4];
  float* out = (float*)d_out;

  // workspace layout (~12.68 MB)
  char* ws = (char*)d_ws;
  unsigned short* en = (unsigned short*)ws;              // 12582912 B
  size_t off = (size_t)B_N * D_K * 2;
  float* rse    = (float*)(ws + off);                    // 32768 B
  int*   hist   = (int*)(ws + off + 32768);              // 28 B (pad to 4096)
  float* contrP = (float*)(ws + off + 36864);            // 64 slots * 64 B = 4096 B
  float* T      = (float*)(ws + off + 40960);            // 7*768*4 = 21504 B
  float* celoss = (float*)(ws + off + 62464);            // 32768 B (fully written)

  hipMemsetAsync(ws + off, 0, 62464, stream);  // zero rse/hist/contrP/T

  k_norm<<<B_N / 4, 256, 0, stream>>>(cls, en);
  k_hist<<<8, 256, 0, stream>>>(labels, hist);
  k_classum<<<48, 256, 0, stream>>>(en, labels, T);
  k_logits_ce<<<B_N / 4, 256, 0, stream>>>(pooled, labels, W, bias, out + 1, celoss);
  k_scl<<<2080, 256, 0, stream>>>(en, rse);
  k_rowfinal<<<B_N / 4, 256, 0, stream>>>(rse, en, T, labels, hist, celoss, contrP);
  k_final<<<1, 64, 0, stream>>>(contrP, out);
}

// Round 6
// 243.856 us; speedup vs baseline: 1.5970x; 1.2612x over previous
//
#include <hip/hip_runtime.h>
#include <hip/hip_bf16.h>

// BERT_SCL: loss = 0.9 * supcon(cls_emb, labels) + 0.1 * CE(pooled@W.T + b, labels)
// d_out[0] = loss, d_out[1..57344] = logits (8192 x 7, f32)
//
// supcon: en = rows of cls_emb normalized, scaled by 1/sqrt(TEMP), cast bf16.
// S_ij = en_i . en_j <= M = 1/TEMP -> fixed-max logsumexp (no online rescale).
// possum_i = en_i . T_{l_i} - ||en_i||^2 (positive mask is linear in S), so the
// big MFMA kernel computes ONLY exp-sums. S symmetric -> tiles bi <= bj (2080),
// off-diag tiles emit row AND col exp-sums. Supertile swizzle (8x8) for L2.
// r5 lesson: k_classum at 48 blocks was latency-bound (~90 us, 0.75 blk/CU).
// Now two-stage: 64x partial sums (direct stores) + reduce. Fallback to the
// atomic version if ws_size is too small (deterministic per-process).
// r4 lesson kept: never force waves/EU; VGPR 112 -> 4 blocks/CU is the tier.

#define B_N 8192
#define D_K 768
#define NLAB 7
#define MBOUND 3.3333333333333335f /* 1/TEMP */
#define RTINV 1.8257418583505538f  /* 1/sqrt(TEMP) */

typedef short s16x8 __attribute__((ext_vector_type(8)));
typedef float f32x4 __attribute__((ext_vector_type(4)));

__device__ __forceinline__ void gl2lds16(const void* g, void* l) {
  __builtin_amdgcn_global_load_lds(
      (const __attribute__((address_space(1))) void*)g,
      (__attribute__((address_space(3))) void*)l, 16, 0, 0);
}

__device__ __forceinline__ float bf16u_to_f(unsigned short u) {
  unsigned int w = ((unsigned int)u) << 16;
  return __uint_as_float(w);
}

// ---- kernel 1: normalize cls rows -> bf16 en (scaled by 1/sqrt(TEMP)) ----
__global__ __launch_bounds__(256) void k_norm(const float* __restrict__ cls,
                                              unsigned short* __restrict__ en) {
  int row = blockIdx.x * 4 + (threadIdx.x >> 6);
  int lane = threadIdx.x & 63;
  const float4* src = (const float4*)(cls + (size_t)row * D_K);
  float4 x[3];
  float ss = 0.f;
#pragma unroll
  for (int j = 0; j < 3; ++j) {
    x[j] = src[j * 64 + lane];
    ss += x[j].x * x[j].x + x[j].y * x[j].y + x[j].z * x[j].z + x[j].w * x[j].w;
  }
#pragma unroll
  for (int m = 1; m < 64; m <<= 1) ss += __shfl_xor(ss, m);
  float sc = rsqrtf(ss) * RTINV;
  ushort4* dst = (ushort4*)(en + (size_t)row * D_K);
#pragma unroll
  for (int j = 0; j < 3; ++j) {
    const float* xv = reinterpret_cast<const float*>(&x[j]);
    ushort4 o;
    unsigned short* ov = reinterpret_cast<unsigned short*>(&o);
#pragma unroll
    for (int k = 0; k < 4; ++k) {
      __hip_bfloat16 h = __float2bfloat16(xv[k] * sc);
      ov[k] = *reinterpret_cast<unsigned short*>(&h);
    }
    dst[j * 64 + lane] = o;
  }
}

// ---- kernel 1b: label histogram ----
__global__ __launch_bounds__(256) void k_hist(const int* __restrict__ labels,
                                              int* __restrict__ hist) {
  int cnt[NLAB];
#pragma unroll
  for (int c = 0; c < NLAB; ++c) cnt[c] = 0;
  int base = blockIdx.x * 1024 + threadIdx.x;
#pragma unroll
  for (int j = 0; j < 4; ++j) {
    int lab = labels[base + j * 256];
#pragma unroll
    for (int c = 0; c < NLAB; ++c) cnt[c] += (lab == c);
  }
#pragma unroll
  for (int c = 0; c < NLAB; ++c)
#pragma unroll
    for (int m = 1; m < 64; m <<= 1) cnt[c] += __shfl_xor(cnt[c], m);
  if ((threadIdx.x & 63) == 0)
#pragma unroll
    for (int c = 0; c < NLAB; ++c) atomicAdd(&hist[c], cnt[c]);
}

// ---- class sums, stage A: 64 blocks x 192 thr; block g sums rows [g*128,g*128+128)
// into partial[g][c][k] (direct stores, no atomics). Thread t owns cols [t*4,t*4+4).
__global__ __launch_bounds__(192) void k_classumA(const unsigned short* __restrict__ en,
                                                  const int* __restrict__ labels,
                                                  float* __restrict__ partial) {
  int g = blockIdx.x, t = threadIdx.x;
  float acc[NLAB][4];
#pragma unroll
  for (int c = 0; c < NLAB; ++c)
#pragma unroll
    for (int k = 0; k < 4; ++k) acc[c][k] = 0.f;
  int r0 = g * 128;
  for (int r = 0; r < 128; r += 4) {
    int lab[4];
    ushort4 u[4];
#pragma unroll
    for (int q = 0; q < 4; ++q) {
      int row = r0 + r + q;
      lab[q] = labels[row];
      u[q] = *(const ushort4*)(en + (size_t)row * D_K + t * 4);
    }
#pragma unroll
    for (int q = 0; q < 4; ++q) {
      float x0 = bf16u_to_f(u[q].x), x1 = bf16u_to_f(u[q].y);
      float x2 = bf16u_to_f(u[q].z), x3 = bf16u_to_f(u[q].w);
#pragma unroll
      for (int c = 0; c < NLAB; ++c) {
        bool m = (lab[q] == c);
        acc[c][0] += m ? x0 : 0.f;
        acc[c][1] += m ? x1 : 0.f;
        acc[c][2] += m ? x2 : 0.f;
        acc[c][3] += m ? x3 : 0.f;
      }
    }
  }
  float* dst = partial + (size_t)g * (NLAB * D_K);
#pragma unroll
  for (int c = 0; c < NLAB; ++c) {
    float4 v = {acc[c][0], acc[c][1], acc[c][2], acc[c][3]};
    *(float4*)(dst + c * D_K + t * 4) = v;
  }
}

// ---- class sums, stage B: T[idx] = sum_g partial[g][idx], idx < 7*768 ----
__global__ __launch_bounds__(256) void k_classumB(const float* __restrict__ partial,
                                                  float* __restrict__ T) {
  int idx = blockIdx.x * 256 + threadIdx.x;  // 21 blocks -> 5376
  float v = 0.f;
  for (int g = 0; g < 64; ++g) v += partial[(size_t)g * (NLAB * D_K) + idx];
  T[idx] = v;
}

// ---- class sums, fallback (small ws): r5 atomic version, needs T pre-zeroed ----
__global__ __launch_bounds__(256) void k_classum_atomic(
    const unsigned short* __restrict__ en, const int* __restrict__ labels,
    float* __restrict__ T) {
  int g = blockIdx.x / 3;
  int kk = (blockIdx.x % 3) * 256 + threadIdx.x;
  float acc[NLAB];
#pragma unroll
  for (int c = 0; c < NLAB; ++c) acc[c] = 0.f;
  int r0 = g * 512;
  for (int r = 0; r < 512; ++r) {
    int row = r0 + r;
    int lab = labels[row];
    float x = bf16u_to_f(en[(size_t)row * D_K + kk]);
#pragma unroll
    for (int c = 0; c < NLAB; ++c) acc[c] += (lab == c) ? x : 0.f;
  }
#pragma unroll
  for (int c = 0; c < NLAB; ++c) atomicAdd(&T[c * D_K + kk], acc[c]);
}

// ---- kernel 2: logits = pooled @ W.T + b ; per-row CE to array ----
__global__ __launch_bounds__(256) void k_logits_ce(
    const float* __restrict__ pooled, const int* __restrict__ labels,
    const float* __restrict__ W, const float* __restrict__ bias,
    float* __restrict__ logits_out, float* __restrict__ celoss) {
  int row = blockIdx.x * 4 + (threadIdx.x >> 6);
  int lane = threadIdx.x & 63;
  const float4* p4 = (const float4*)(pooled + (size_t)row * D_K);
  float acc[NLAB];
#pragma unroll
  for (int c = 0; c < NLAB; ++c) acc[c] = 0.f;
#pragma unroll
  for (int j = 0; j < 3; ++j) {
    float4 x = p4[j * 64 + lane];
#pragma unroll
    for (int c = 0; c < NLAB; ++c) {
      float4 w = ((const float4*)(W + c * D_K))[j * 64 + lane];
      acc[c] += x.x * w.x + x.y * w.y + x.z * w.z + x.w * w.w;
    }
  }
#pragma unroll
  for (int c = 0; c < NLAB; ++c)
#pragma unroll
    for (int m = 1; m < 64; m <<= 1) acc[c] += __shfl_xor(acc[c], m);
  if (lane == 0) {
    float l[NLAB], mx = -1e30f;
#pragma unroll
    for (int c = 0; c < NLAB; ++c) { l[c] = acc[c] + bias[c]; mx = fmaxf(mx, l[c]); }
    float se = 0.f;
#pragma unroll
    for (int c = 0; c < NLAB; ++c) se += __expf(l[c] - mx);
    float lse = mx + __logf(se);
    celoss[row] = lse - l[labels[row]];
    float* o = logits_out + (size_t)row * NLAB;
#pragma unroll
    for (int c = 0; c < NLAB; ++c) o[c] = l[c];
  }
}

// ---- kernel 3: exp-sum S-tiles via bf16 MFMA, upper-triangular, supertile order ----
__global__ __launch_bounds__(256) void k_scl(const unsigned short* __restrict__ en,
                                             float* __restrict__ rse) {
  __shared__ __align__(16) unsigned short As[128 * 64];
  __shared__ __align__(16) unsigned short Bs[128 * 64];

  int rem = blockIdx.x;
  int BI = 0, BJ = 0;
  for (;;) {
    int sz = (BI == BJ) ? 36 : 64;
    if (rem < sz) break;
    rem -= sz;
    if (++BJ == 8) { ++BI; BJ = BI; }
  }
  int bi, bj;
  if (BI == BJ) {
    int r = 0, w = 8;
    while (rem >= w) { rem -= w; ++r; --w; }
    bi = BI * 8 + r;
    bj = BJ * 8 + r + rem;
  } else {
    bi = BI * 8 + (rem >> 3);
    bj = BJ * 8 + (rem & 7);
  }

  const int i0 = bi * 128, j0 = bj * 128;
  const int tid = threadIdx.x, wv = tid >> 6, lane = tid & 63;
  const int quad = lane >> 4, cix = lane & 15;
  const int rowTile = 64 * (wv >> 1), colTile = 64 * (wv & 1);

  f32x4 acc[4][4] = {};

  for (int kc = 0; kc < 12; ++kc) {
    __syncthreads();
#pragma unroll
    for (int it = 0; it < 4; ++it) {
      int s = it * 256 + tid;
      int r = s >> 3;
      int c = ((s & 7) - r) & 7;  // inverse of write swizzle
      int lbase = (it * 256 + wv * 64) * 16;  // wave-uniform LDS base (bytes)
      gl2lds16(en + (size_t)(i0 + r) * D_K + kc * 64 + c * 8, (char*)As + lbase);
      gl2lds16(en + (size_t)(j0 + r) * D_K + kc * 64 + c * 8, (char*)Bs + lbase);
    }
    __syncthreads();
#pragma unroll
    for (int h = 0; h < 2; ++h) {
      const int cc = quad + 4 * h;
      s16x8 aF[4];
#pragma unroll
      for (int mt = 0; mt < 4; ++mt) {
        int r = rowTile + 16 * mt + cix;
        aF[mt] = *reinterpret_cast<const s16x8*>((const char*)As +
                                                 (r * 8 + ((cc + r) & 7)) * 16);
      }
#pragma unroll
      for (int nt = 0; nt < 4; ++nt) {  // bF streamed: 1 live frag
        int r = colTile + 16 * nt + cix;
        s16x8 bF = *reinterpret_cast<const s16x8*>((const char*)Bs +
                                                   (r * 8 + ((cc + r) & 7)) * 16);
#pragma unroll
        for (int mt = 0; mt < 4; ++mt)
          acc[mt][nt] = __builtin_amdgcn_mfma_f32_16x16x32_bf16(
              aF[mt], bF, acc[mt][nt], 0, 0, 0);
      }
    }
  }

  // ---- epilogue: exp-sums only ----
  if (bi != bj) {
    float ce_col[4] = {0.f, 0.f, 0.f, 0.f};
#pragma unroll
    for (int mt = 0; mt < 4; ++mt) {
      int rowbase = i0 + rowTile + 16 * mt + quad * 4;
      float rs_e[4] = {0.f, 0.f, 0.f, 0.f};
#pragma unroll
      for (int nt = 0; nt < 4; ++nt) {
#pragma unroll
        for (int rg = 0; rg < 4; ++rg) {
          float e = __expf(acc[mt][nt][rg] - MBOUND);
          rs_e[rg] += e;
          ce_col[nt] += e;
        }
      }
#pragma unroll
      for (int rg = 0; rg < 4; ++rg)
#pragma unroll
        for (int m = 1; m <= 8; m <<= 1) rs_e[rg] += __shfl_xor(rs_e[rg], m);
      if (cix == 0)
#pragma unroll
        for (int rg = 0; rg < 4; ++rg) atomicAdd(&rse[rowbase + rg], rs_e[rg]);
    }
#pragma unroll
    for (int nt = 0; nt < 4; ++nt) {
      ce_col[nt] += __shfl_xor(ce_col[nt], 16);
      ce_col[nt] += __shfl_xor(ce_col[nt], 32);
    }
    if (quad == 0)
#pragma unroll
      for (int nt = 0; nt < 4; ++nt)
        atomicAdd(&rse[j0 + colTile + 16 * nt + cix], ce_col[nt]);
  } else {
#pragma unroll
    for (int mt = 0; mt < 4; ++mt) {
      int rowbase = i0 + rowTile + 16 * mt + quad * 4;
      float rs_e[4] = {0.f, 0.f, 0.f, 0.f};
#pragma unroll
      for (int nt = 0; nt < 4; ++nt) {
        int gcol = j0 + colTile + 16 * nt + cix;
#pragma unroll
        for (int rg = 0; rg < 4; ++rg) {
          bool dg = (rowbase + rg) == gcol;
          rs_e[rg] += dg ? 0.f : __expf(acc[mt][nt][rg] - MBOUND);
        }
      }
#pragma unroll
      for (int rg = 0; rg < 4; ++rg)
#pragma unroll
        for (int m = 1; m <= 8; m <<= 1) rs_e[rg] += __shfl_xor(rs_e[rg], m);
      if (cix == 0)
#pragma unroll
        for (int rg = 0; rg < 4; ++rg) atomicAdd(&rse[rowbase + rg], rs_e[rg]);
    }
  }
}

// ---- kernel 4: per-row: possum via en.T[l] - selfdot; combine; 64-slot partials ----
__global__ __launch_bounds__(256) void k_rowfinal(const float* __restrict__ rse,
                                                  const unsigned short* __restrict__ en,
                                                  const float* __restrict__ T,
                                                  const int* __restrict__ labels,
                                                  const int* __restrict__ hist,
                                                  const float* __restrict__ celoss,
                                                  float* __restrict__ contrP) {
  __shared__ float part[4];
  int wv = threadIdx.x >> 6, lane = threadIdx.x & 63;
  int row = blockIdx.x * 4 + wv;
  int l = labels[row];
  const ushort4* e4 = (const ushort4*)(en + (size_t)row * D_K);
  const float4* t4 = (const float4*)(T + (size_t)l * D_K);
  float pd = 0.f, sd = 0.f;
#pragma unroll
  for (int j = 0; j < 3; ++j) {
    ushort4 u = e4[j * 64 + lane];
    float4 t = t4[j * 64 + lane];
    float a0 = bf16u_to_f(u.x), a1 = bf16u_to_f(u.y);
    float a2 = bf16u_to_f(u.z), a3 = bf16u_to_f(u.w);
    pd += a0 * t.x + a1 * t.y + a2 * t.z + a3 * t.w;
    sd += a0 * a0 + a1 * a1 + a2 * a2 + a3 * a3;
  }
#pragma unroll
  for (int m = 1; m < 64; m <<= 1) {
    pd += __shfl_xor(pd, m);
    sd += __shfl_xor(sd, m);
  }
  if (lane == 0) {
    int ni = hist[l] - 1;
    float per = 0.f;
    if (ni > 0) {
      float possum = pd - sd;
      per = MBOUND + __logf(rse[row]) - possum / (float)ni;
    }
    part[wv] = 0.9f * per + (0.1f / (float)B_N) * celoss[row];
  }
  __syncthreads();
  if (threadIdx.x == 0) {
    float v = part[0] + part[1] + part[2] + part[3];
    atomicAdd(&contrP[(blockIdx.x & 63) * 16], v);
  }
}

// ---- kernel 5: reduce 64 partials -> loss ----
__global__ void k_final(const float* __restrict__ contrP, float* __restrict__ out) {
  float v = contrP[threadIdx.x * 16];
#pragma unroll
  for (int m = 1; m < 64; m <<= 1) v += __shfl_xor(v, m);
  if (threadIdx.x == 0) out[0] = v;
}

extern "C" void kernel_launch(void* const* d_in, const int* in_sizes, int n_in,
                              void* d_out, int out_size, void* d_ws, size_t ws_size,
                              hipStream_t stream) {
  const float* cls    = (const float*)d_in[0];
  const float* pooled = (const float*)d_in[1];
  const int*   labels = (const int*)d_in[2];
  const float* W      = (const float*)d_in[3];
  const float* bias   = (const float*)d_in[4];
  float* out = (float*)d_out;

  // workspace layout
  char* ws = (char*)d_ws;
  unsigned short* en = (unsigned short*)ws;            // 12582912 B
  size_t off = (size_t)B_N * D_K * 2;
  float* rse     = (float*)(ws + off);                 // +0      (32768 B)
  int*   hist    = (int*)(ws + off + 32768);           // +32768  (4096 B)
  float* contrP  = (float*)(ws + off + 36864);         // +36864  (4096 B)
  float* celoss  = (float*)(ws + off + 40960);         // +40960  (32768 B, fully written)
  float* T       = (float*)(ws + off + 73728);         // +73728  (21504 B -> pad 24576)
  float* partial = (float*)(ws + off + 98304);         // +98304  (64*5376*4 = 1376256 B)
  size_t need_partial = off + 98304 + 64 * (size_t)(NLAB * D_K) * 4;
  bool big_ws = ws_size >= need_partial;

  // zero rse/hist/contrP (+T when the atomic fallback needs it)
  hipMemsetAsync(ws + off, 0, big_ws ? 40960 : 98304, stream);

  k_norm<<<B_N / 4, 256, 0, stream>>>(cls, en);
  k_hist<<<8, 256, 0, stream>>>(labels, hist);
  if (big_ws) {
    k_classumA<<<64, 192, 0, stream>>>(en, labels, partial);
    k_classumB<<<21, 256, 0, stream>>>(partial, T);
  } else {
    k_classum_atomic<<<48, 256, 0, stream>>>(en, labels, T);
  }
  k_logits_ce<<<B_N / 4, 256, 0, stream>>>(pooled, labels, W, bias, out + 1, celoss);
  k_scl<<<2080, 256, 0, stream>>>(en, rse);
  k_rowfinal<<<B_N / 4, 256, 0, stream>>>(rse, en, T, labels, hist, celoss, contrP);
  k_final<<<1, 64, 0, stream>>>(contrP, out);
}